// Round 11
// baseline (217.729 us; speedup 1.0000x reference)
//
#include <hip/hip_runtime.h>
#include <cstdint>
#include <cstddef>

#define TOKENS 8192
#define DIN    4096
#define DOUT   4096

typedef int int4v  __attribute__((ext_vector_type(4)));
typedef int int16v __attribute__((ext_vector_type(16)));

// ---------------------------------------------------------------------------
// Kernel 1: per-token dynamic quantization (unchanged, near HBM-bound).
// ---------------------------------------------------------------------------
__global__ __launch_bounds__(256) void quant_rows(const float* __restrict__ x,
                                                  int* __restrict__ xq,
                                                  float* __restrict__ ascale,
                                                  int* __restrict__ rsum) {
  const int row = blockIdx.x;
  const int t = threadIdx.x;
  const float4* xr = (const float4*)(x + (size_t)row * DIN);
  float4 v[4];
#pragma unroll
  for (int i = 0; i < 4; ++i) v[i] = xr[i * 256 + t];

  float m = 0.f;
#pragma unroll
  for (int i = 0; i < 4; ++i) {
    m = fmaxf(m, fabsf(v[i].x)); m = fmaxf(m, fabsf(v[i].y));
    m = fmaxf(m, fabsf(v[i].z)); m = fmaxf(m, fabsf(v[i].w));
  }
#pragma unroll
  for (int off = 32; off; off >>= 1) m = fmaxf(m, __shfl_xor(m, off));

  __shared__ float wmax[4];
  __shared__ int   wsum[4];
  const int lane = t & 63, wid = t >> 6;
  if (lane == 0) wmax[wid] = m;
  __syncthreads();
  m = fmaxf(fmaxf(wmax[0], wmax[1]), fmaxf(wmax[2], wmax[3]));

  const float s = m * (1.0f / 127.0f);
  const float sdiv = (m > 0.f) ? s : 1.0f;

  int ssum = 0;
#pragma unroll
  for (int i = 0; i < 4; ++i) {
    float q;
    q = fminf(fmaxf(rintf(v[i].x / sdiv), -127.f), 127.f); const int b0 = (int)q;
    q = fminf(fmaxf(rintf(v[i].y / sdiv), -127.f), 127.f); const int b1 = (int)q;
    q = fminf(fmaxf(rintf(v[i].z / sdiv), -127.f), 127.f); const int b2 = (int)q;
    q = fminf(fmaxf(rintf(v[i].w / sdiv), -127.f), 127.f); const int b3 = (int)q;
    ssum += b0 + b1 + b2 + b3;
    xq[(size_t)row * 1024 + i * 256 + t] =
        (b0 & 255) | ((b1 & 255) << 8) | ((b2 & 255) << 16) | ((b3 & 255) << 24);
  }
#pragma unroll
  for (int off = 32; off; off >>= 1) ssum += __shfl_xor(ssum, off);
  if (lane == 0) wsum[wid] = ssum;
  __syncthreads();
  if (t == 0) {
    rsum[row]   = wsum[0] + wsum[1] + wsum[2] + wsum[3];
    ascale[row] = s;
  }
}

// ---------------------------------------------------------------------------
// Kernel 2: weight int32 -> packed int8 (unchanged).
// ---------------------------------------------------------------------------
__global__ __launch_bounds__(256) void wconv(const int* __restrict__ w,
                                             int* __restrict__ w8) {
  const int idx = blockIdx.x * 256 + threadIdx.x;
  const int4 v = ((const int4*)w)[idx];
  w8[idx] = (v.x & 255) | ((v.y & 255) << 8) | ((v.z & 255) << 16) | ((v.w & 255) << 24);
}

// ---------------------------------------------------------------------------
// Kernel 3: i8 GEMM, 256x256 tile, 4 WAVES x (128x128 per wave).
// LDS-traffic reduction round: reads/CU-tile 96 -> 64 b128 (frag reuse 4x4).
//  - 256 thr = 4 waves (2M x 2N), per-wave 128x128 C, acc[4][4] = 256 VGPR
//    -> 1 wave/SIMD (launch_bounds(256,1)); compile-time pipelining covers
//    latency: every RD is issued one full MFMA16 cluster (~586 cyc) early.
//  - LDS 128 KiB: ring of 4 tile-buffers [Au0|Au1|Bu0|Bu1] x 8 KiB.
//  - Super-step (R10-verified skeleton, each SS exactly once): stage {S+2,
//    S+3} up-front (16 gloads), compute tiles S,S+1, one vmcnt(0)+barrier.
//  - R7-verified involution swizzle for staging source + fragment reads.
// ---------------------------------------------------------------------------
#define GLOAD(G_, L_) __builtin_amdgcn_global_load_lds(                       \
      (const __attribute__((address_space(1))) void*)(G_),                    \
      (__attribute__((address_space(3))) void*)(L_), 16, 0, 0)

#define STAGE(TT_)                                                            \
  do {                                                                        \
    char* Wb_ = lds + ((TT_) & 3) * 32768;                                    \
    const size_t k_ = (size_t)(TT_) * 64;                                     \
    GLOAD(pA + k_,            Wb_ + ldst);                                    \
    GLOAD(pA + 64*DIN  + k_,  Wb_ + 4096  + ldst);                            \
    GLOAD(pA + 128*DIN + k_,  Wb_ + 8192  + ldst);                            \
    GLOAD(pA + 192*DIN + k_,  Wb_ + 12288 + ldst);                            \
    GLOAD(pB + k_,            Wb_ + 16384 + ldst);                            \
    GLOAD(pB + 64*DIN  + k_,  Wb_ + 20480 + ldst);                            \
    GLOAD(pB + 128*DIN + k_,  Wb_ + 24576 + ldst);                            \
    GLOAD(pB + 192*DIN + k_,  Wb_ + 28672 + ldst);                            \
  } while (0)

#define RD(AV_, BV_, L_, AO_, BO_)                                            \
    _Pragma("unroll")                                                         \
    for (int mi = 0; mi < 4; ++mi)                                            \
      AV_[mi] = *(const int4v*)((L_) + (AO_) + mi * 2048);                    \
    _Pragma("unroll")                                                         \
    for (int ni = 0; ni < 4; ++ni)                                            \
      BV_[ni] = *(const int4v*)((L_) + (BO_) + ni * 2048);

#define MFMA16(AV_, BV_)                                                      \
  __builtin_amdgcn_s_setprio(1);                                              \
  _Pragma("unroll")                                                           \
  for (int mi = 0; mi < 4; ++mi)                                              \
    _Pragma("unroll")                                                         \
    for (int ni = 0; ni < 4; ++ni)                                            \
      acc[mi][ni] = __builtin_amdgcn_mfma_i32_32x32x32_i8(                    \
          AV_[mi], BV_[ni], acc[mi][ni], 0, 0, 0);                            \
  __builtin_amdgcn_s_setprio(0);

// Super-step: [stage S+2,S+3] | k1(S)->aB,bB | MFMA k0(S) | k0(S+1)->aA,bA |
//             MFMA k1(S) | k1(S+1)->aB,bB | MFMA k0(S+1) | MFMA k1(S+1) |
//             [vmcnt(0) barrier sched_barrier; k0(S+2)->aA,bA]
#define SUPER(S_, STG_, BAR_)                                                 \
  do {                                                                        \
    if (STG_) { STAGE((S_) + 2); STAGE((S_) + 3); }                           \
    {                                                                         \
      const char* L0 = lds + ((S_) & 3) * 32768;                              \
      const char* L1 = lds + (((S_) + 1) & 3) * 32768;                        \
      RD(aB, bB, L0, aoff1, boff1)       /* k1(S)   */                        \
      MFMA16(aA, bA)                     /* k0(S)   */                        \
      RD(aA, bA, L1, aoff0, boff0)       /* k0(S+1) */                        \
      MFMA16(aB, bB)                     /* k1(S)   */                        \
      RD(aB, bB, L1, aoff1, boff1)       /* k1(S+1) */                        \
      MFMA16(aA, bA)                     /* k0(S+1) */                        \
      MFMA16(aB, bB)                     /* k1(S+1) */                        \
    }                                                                         \
    if (BAR_) {                                                               \
      asm volatile("s_waitcnt vmcnt(0)" ::: "memory");                        \
      __builtin_amdgcn_s_barrier();                                           \
      __builtin_amdgcn_sched_barrier(0);                                      \
      const char* L2 = lds + (((S_) + 2) & 3) * 32768;                        \
      RD(aA, bA, L2, aoff0, boff0)       /* k0(S+2) */                        \
    }                                                                         \
  } while (0)

__global__ __launch_bounds__(256, 1) void gemm_i8(
    const char* __restrict__ xq, const char* __restrict__ w8,
    const float* __restrict__ ascale, const int* __restrict__ rsum,
    const float* __restrict__ wscale, const float* __restrict__ woff,
    const float* __restrict__ bias, float* __restrict__ y) {

  // 4 ring buffers x [Au0|Au1|Bu0|Bu1] x 8 KiB = 128 KiB
  __shared__ __align__(16) char lds[131072];

  const int bid = blockIdx.x;
  const int tm = bid >> 4;            // 32 M-tiles
  const int tn = bid & 15;            // 16 N-tiles
  const int t = threadIdx.x;          // 0..255
  const int lane = t & 63, wid = t >> 6;
  const int wmI = wid >> 1;           // 0..1 (M)
  const int wnI = wid & 1;            // 0..1 (N)

  // ---- staging source: involution (R7, verified). L = t*16 (0..4095);
  //      second chunk L+4096 leaves involution bits (7,8,10) unchanged
  //      -> same scol, srow+64. ----
  const int S_ = (t * 16) ^ (((t >> 3) & 3) << 4) ^ (((t >> 6) & 1) << 6);
  const int srow = S_ >> 6;                             // 0..63
  const int scol = S_ & 63;

  const char* pA = xq + (size_t)(tm * 256 + srow) * DIN + scol;
  const char* pB = w8 + (size_t)(tn * 256 + srow) * DIN + scol;
  const int ldst = t * 16;                              // LINEAR LDS dest

  // ---- fragment read offsets (R7 involution, verified) ----
  const int mask  = (((lane >> 1) & 3) << 4) ^ (((lane >> 4) & 1) << 6);
  const int arow  = (lane & 31) * 64 + (lane >> 5) * 16;
  const int aoff0 = wmI * 8192 + ((arow +  0) ^ mask);
  const int aoff1 = wmI * 8192 + ((arow + 32) ^ mask);
  const int boff0 = (2 + wnI) * 8192 + ((arow +  0) ^ mask);
  const int boff1 = (2 + wnI) * 8192 + ((arow + 32) ^ mask);

  int16v acc[4][4];
#pragma unroll
  for (int mi = 0; mi < 4; ++mi)
#pragma unroll
    for (int ni = 0; ni < 4; ++ni)
#pragma unroll
      for (int rg = 0; rg < 16; ++rg) acc[mi][ni][rg] = 0;

  int4v aA[4], aB[4], bA[4], bB[4];

  // ---- prologue: stage K-tiles 0..3 (32 gloads); force {0,1}; read k0(0) ----
  STAGE(0); STAGE(1); STAGE(2); STAGE(3);
  asm volatile("s_waitcnt vmcnt(16)" ::: "memory");   // tiles 0,1 landed
  __builtin_amdgcn_s_barrier();
  __builtin_amdgcn_sched_barrier(0);
  RD(aA, bA, lds, aoff0, boff0)

  // ---- main loop: 32 super-steps of 2 K-tiles, each EXACTLY ONCE ----
  SUPER(0, 0, 1);                          // tiles 0,1 (bufs 2,3 from prologue)
  for (int S = 2; S <= 60; S += 2)         // SS 2..60; SS(60) stages 62,63
    SUPER(S, 1, 1);
  SUPER(62, 0, 0);                         // tiles 62,63; no stage/barrier

  // ---- epilogue: zp-correction + dequant + bias ----
  // C/D 32x32: col = lane&31, row = (rg&3) + 8*(rg>>2) + 4*(lane>>5)
  const int rb0 = tm * 256 + wmI * 128 + 4 * (lane >> 5);
  const int cb0 = tn * 256 + wnI * 128 + (lane & 31);
  float ws_[4], wo_[4], bi_[4];
#pragma unroll
  for (int ni = 0; ni < 4; ++ni) {
    ws_[ni] = wscale[cb0 + ni * 32];
    wo_[ni] = woff[cb0 + ni * 32];
    bi_[ni] = bias[cb0 + ni * 32];
  }
#pragma unroll
  for (int mi = 0; mi < 4; ++mi) {
#pragma unroll
    for (int rg = 0; rg < 16; ++rg) {
      const int r = rb0 + mi * 32 + (rg & 3) + 8 * (rg >> 2);
      const float as_ = ascale[r];
      const float rs_ = (float)rsum[r];
      float* yr = y + (size_t)r * DOUT + cb0;
#pragma unroll
      for (int ni = 0; ni < 4; ++ni)
        yr[ni * 32] = ((float)acc[mi][ni][rg] + rs_ * wo_[ni]) * (as_ * ws_[ni]) + bi_[ni];
    }
  }
}

// ---------------------------------------------------------------------------
extern "C" void kernel_launch(void* const* d_in, const int* in_sizes, int n_in,
                              void* d_out, int out_size, void* d_ws, size_t ws_size,
                              hipStream_t stream) {
  const float* x      = (const float*)d_in[0];
  const int*   w      = (const int*)  d_in[1];
  const float* wscale = (const float*)d_in[2];
  const float* woff   = (const float*)d_in[3];
  const float* bias   = (const float*)d_in[4];
  float* y = (float*)d_out;

  char* ws = (char*)d_ws;
  char*  xq     = ws;                                 // 33,554,432 B
  char*  w8     = ws + (size_t)TOKENS * DIN;          // 16,777,216 B
  float* ascale = (float*)(w8 + (size_t)DOUT * DIN);  // 32,768 B
  int*   rsum   = (int*)(ascale + TOKENS);            // 32,768 B

  hipLaunchKernelGGL(quant_rows, dim3(TOKENS), dim3(256), 0, stream,
                     x, (int*)xq, ascale, rsum);
  hipLaunchKernelGGL(wconv, dim3((DOUT * DIN / 4) / 256), dim3(256), 0, stream,
                     w, (int*)w8);
  hipLaunchKernelGGL(gemm_i8, dim3((TOKENS / 256) * (DOUT / 256)), dim3(256), 0, stream,
                     xq, w8, ascale, rsum, wscale, woff, bias, y);
}